// Round 1
// baseline (379.924 us; speedup 1.0000x reference)
//
#include <hip/hip_runtime.h>
#include <hip/hip_bf16.h>
#include <math.h>

// Problem: x(32,512,768) fp32 -> LayerNorm(768) -> Linear 768x3072 + bias -> exact GELU
// M = 16384 rows, K = 768, N = 3072. Output fp32.
#define M_ROWS 16384
#define K_DIM  768
#define N_DIM  3072

// ---------- helpers ----------
__device__ __forceinline__ unsigned short f2bf(float f) {
    unsigned int u = __float_as_uint(f);
    unsigned int r = (u + 0x7fffu + ((u >> 16) & 1u)) >> 16;   // round-to-nearest-even
    return (unsigned short)r;
}

typedef __bf16 bf16x8 __attribute__((ext_vector_type(8)));
typedef float  f32x4  __attribute__((ext_vector_type(4)));

__device__ __forceinline__ void async16(const unsigned short* g, unsigned short* l) {
    __builtin_amdgcn_global_load_lds(
        (const __attribute__((address_space(1))) unsigned int*)g,
        (__attribute__((address_space(3))) unsigned int*)l,
        16, 0, 0);
}

// ---------- 1) LayerNorm + cast to bf16 ----------
// one wave (64 lanes) per row; 768/64 = 12 elements per lane
__global__ __launch_bounds__(256) void ln_kernel(const float* __restrict__ x,
                                                 const float* __restrict__ gamma,
                                                 const float* __restrict__ beta,
                                                 unsigned short* __restrict__ xn) {
    int wave = threadIdx.x >> 6;
    int lane = threadIdx.x & 63;
    int row  = blockIdx.x * 4 + wave;
    const float* xr = x + (size_t)row * K_DIM;

    float v[12];
    float s = 0.f, ss = 0.f;
#pragma unroll
    for (int i = 0; i < 12; i++) {
        v[i] = xr[lane + 64 * i];
        s  += v[i];
        ss += v[i] * v[i];
    }
#pragma unroll
    for (int off = 32; off; off >>= 1) {
        s  += __shfl_xor(s,  off, 64);
        ss += __shfl_xor(ss, off, 64);
    }
    float mu   = s * (1.f / K_DIM);
    float var  = ss * (1.f / K_DIM) - mu * mu;
    float rstd = rsqrtf(var + 1e-12f);

    unsigned short* xo = xn + (size_t)row * K_DIM;
#pragma unroll
    for (int i = 0; i < 12; i++) {
        int c = lane + 64 * i;
        float y = (v[i] - mu) * rstd * gamma[c] + beta[c];
        xo[c] = f2bf(y);
    }
}

// ---------- 2) W [K,N] fp32 -> Wt [N,K] bf16 (LDS-tiled transpose) ----------
__global__ __launch_bounds__(256) void wcast_kernel(const float* __restrict__ W,
                                                    unsigned short* __restrict__ wt) {
    __shared__ float tile[32][33];
    int bx = blockIdx.x;  // n tile
    int by = blockIdx.y;  // k tile
    int tx = threadIdx.x; // 0..31
    int ty = threadIdx.y; // 0..7
#pragma unroll
    for (int r = 0; r < 4; r++) {
        int k = by * 32 + ty + 8 * r;
        int n = bx * 32 + tx;
        tile[ty + 8 * r][tx] = W[(size_t)k * N_DIM + n];
    }
    __syncthreads();
#pragma unroll
    for (int r = 0; r < 4; r++) {
        int n = bx * 32 + ty + 8 * r;
        int k = by * 32 + tx;
        wt[(size_t)n * K_DIM + k] = f2bf(tile[tx][ty + 8 * r]);
    }
}

// ---------- 3) GEMM: C[M,N] = xn[M,K] * Wt[N,K]^T, epilogue bias + exact GELU ----------
// 128x128 block tile, BK=64, 256 threads = 4 waves (2x2), each wave 64x64 via 4x4 MFMA 16x16x32
__global__ __launch_bounds__(256) void gemm_kernel(const unsigned short* __restrict__ A,
                                                   const unsigned short* __restrict__ B,
                                                   const float* __restrict__ bias,
                                                   float* __restrict__ C) {
    __shared__ __attribute__((aligned(16))) unsigned short As[128 * 64];
    __shared__ __attribute__((aligned(16))) unsigned short Bs[128 * 64];

    int tid  = threadIdx.x;
    int lane = tid & 63;
    int wid  = tid >> 6;
    int waveM = wid >> 1;   // 0..1
    int waveN = wid & 1;    // 0..1
    int bm = blockIdx.y;
    int bn = blockIdx.x;

    f32x4 acc[4][4] = {};

    // staging: thread tid covers 16B chunk: row = tid/8 (+32*i), chunk = tid%8
    const unsigned short* Ag = A + (size_t)(bm * 128 + (tid >> 3)) * K_DIM + (tid & 7) * 8;
    const unsigned short* Bg = B + (size_t)(bn * 128 + (tid >> 3)) * K_DIM + (tid & 7) * 8;
    unsigned short* Al = As + tid * 8;  // byte offset tid*16; wave-contiguous
    unsigned short* Bl = Bs + tid * 8;

    int mrow = lane & 15;       // m (or n) within 16
    int quad = lane >> 4;       // 0..3, selects k-octet

    for (int kt = 0; kt < K_DIM / 64; ++kt) {
#pragma unroll
        for (int i = 0; i < 4; i++) {
            async16(Ag + (size_t)i * 32 * K_DIM + kt * 64, Al + i * 2048);
            async16(Bg + (size_t)i * 32 * K_DIM + kt * 64, Bl + i * 2048);
        }
        __syncthreads();   // drains vmcnt: LDS tile visible

#pragma unroll
        for (int s = 0; s < 2; s++) {
            bf16x8 af[4], bfr[4];
#pragma unroll
            for (int i = 0; i < 4; i++)
                af[i] = *(const bf16x8*)(As + (waveM * 64 + i * 16 + mrow) * 64 + s * 32 + quad * 8);
#pragma unroll
            for (int j = 0; j < 4; j++)
                bfr[j] = *(const bf16x8*)(Bs + (waveN * 64 + j * 16 + mrow) * 64 + s * 32 + quad * 8);
#pragma unroll
            for (int i = 0; i < 4; i++)
#pragma unroll
                for (int j = 0; j < 4; j++)
                    acc[i][j] = __builtin_amdgcn_mfma_f32_16x16x32_bf16(af[i], bfr[j], acc[i][j], 0, 0, 0);
        }
        __syncthreads();   // protect LDS before next stage
    }

    // epilogue: C/D layout col = lane&15, row = quad*4 + reg
    int colBase = bn * 128 + waveN * 64 + mrow;
    int rowBase = bm * 128 + waveM * 64 + quad * 4;
#pragma unroll
    for (int j = 0; j < 4; j++) {
        int col = colBase + j * 16;
        float bb = bias[col];
#pragma unroll
        for (int i = 0; i < 4; i++) {
            int row0 = rowBase + i * 16;
#pragma unroll
            for (int r = 0; r < 4; r++) {
                float h = acc[i][j][r] + bb;
                float g = 0.5f * h * (1.0f + erff(h * 0.70710678118654752f));
                C[(size_t)(row0 + r) * N_DIM + col] = g;
            }
        }
    }
}

extern "C" void kernel_launch(void* const* d_in, const int* in_sizes, int n_in,
                              void* d_out, int out_size, void* d_ws, size_t ws_size,
                              hipStream_t stream) {
    const float* x     = (const float*)d_in[0];
    const float* gamma = (const float*)d_in[1];
    const float* beta  = (const float*)d_in[2];
    const float* W     = (const float*)d_in[3];
    const float* bias  = (const float*)d_in[4];
    float* out = (float*)d_out;

    unsigned short* xn = (unsigned short*)d_ws;              // M*K bf16 = 25.2 MB
    unsigned short* wt = xn + (size_t)M_ROWS * K_DIM;        // N*K bf16 = 4.7 MB

    ln_kernel<<<M_ROWS / 4, 256, 0, stream>>>(x, gamma, beta, xn);
    wcast_kernel<<<dim3(N_DIM / 32, K_DIM / 32), dim3(32, 8), 0, stream>>>(W, wt);
    gemm_kernel<<<dim3(N_DIM / 128, M_ROWS / 128), 256, 0, stream>>>(xn, wt, bias, out);
}

// Round 2
// 353.177 us; speedup vs baseline: 1.0757x; 1.0757x over previous
//
#include <hip/hip_runtime.h>
#include <hip/hip_bf16.h>
#include <math.h>

// x(32,512,768) fp32 -> LayerNorm(768) -> Linear 768x3072 + bias -> exact GELU
// M = 16384, K = 768, N = 3072. Output fp32.
#define M_ROWS 16384
#define K_DIM  768
#define N_DIM  3072

typedef __bf16 bf16x8 __attribute__((ext_vector_type(8)));
typedef float  f32x4  __attribute__((ext_vector_type(4)));
typedef unsigned short u16x4 __attribute__((ext_vector_type(4)));

__device__ __forceinline__ unsigned short f2bf(float f) {
    unsigned int u = __float_as_uint(f);
    unsigned int r = (u + 0x7fffu + ((u >> 16) & 1u)) >> 16;   // RNE
    return (unsigned short)r;
}

__device__ __forceinline__ void async16(const unsigned short* g, unsigned short* l) {
    __builtin_amdgcn_global_load_lds(
        (const __attribute__((address_space(1))) unsigned int*)g,
        (__attribute__((address_space(3))) unsigned int*)l,
        16, 0, 0);
}

// tanh-form GELU: 0.5h(1+tanh(0.79788456(h+0.044715h^3))); max |err| vs erf ~1e-3
__device__ __forceinline__ float gelu_fast(float h) {
    float h2 = h * h;
    float z2 = h * __builtin_fmaf(0.0713548162f, h2, 1.5957691216f); // 2*z
    float E  = __expf(z2);                                           // e^{2z}
    float r  = __builtin_amdgcn_rcpf(1.0f + E);                      // (1-tanh)/2
    return h - h * r;                                                // 0.5h(1+tanh)
}

// ---------- 1) LayerNorm + cast to bf16 (vectorized) ----------
__global__ __launch_bounds__(256) void ln_kernel(const float* __restrict__ x,
                                                 const float* __restrict__ gamma,
                                                 const float* __restrict__ beta,
                                                 unsigned short* __restrict__ xn) {
    int wave = threadIdx.x >> 6;
    int lane = threadIdx.x & 63;
    int row  = blockIdx.x * 4 + wave;
    const f32x4* xr = (const f32x4*)(x + (size_t)row * K_DIM);
    const f32x4* g4 = (const f32x4*)gamma;
    const f32x4* b4 = (const f32x4*)beta;

    f32x4 v[3];
    float s = 0.f, ss = 0.f;
#pragma unroll
    for (int q = 0; q < 3; q++) {
        v[q] = xr[lane + 64 * q];
#pragma unroll
        for (int e = 0; e < 4; e++) { s += v[q][e]; ss += v[q][e] * v[q][e]; }
    }
#pragma unroll
    for (int off = 32; off; off >>= 1) {
        s  += __shfl_xor(s,  off, 64);
        ss += __shfl_xor(ss, off, 64);
    }
    float mu   = s * (1.f / K_DIM);
    float var  = ss * (1.f / K_DIM) - mu * mu;
    float rstd = rsqrtf(var + 1e-12f);

    u16x4* xo = (u16x4*)(xn + (size_t)row * K_DIM);
#pragma unroll
    for (int q = 0; q < 3; q++) {
        f32x4 gv = g4[lane + 64 * q];
        f32x4 bv = b4[lane + 64 * q];
        u16x4 o;
#pragma unroll
        for (int e = 0; e < 4; e++)
            o[e] = f2bf((v[q][e] - mu) * rstd * gv[e] + bv[e]);
        xo[lane + 64 * q] = o;
    }
}

// ---------- 2) W [K,N] fp32 -> Wt [N,K] bf16 ----------
__global__ __launch_bounds__(256) void wcast_kernel(const float* __restrict__ W,
                                                    unsigned short* __restrict__ wt) {
    __shared__ float tile[32][33];
    int bx = blockIdx.x, by = blockIdx.y;
    int tx = threadIdx.x, ty = threadIdx.y;
#pragma unroll
    for (int r = 0; r < 4; r++)
        tile[ty + 8 * r][tx] = W[(size_t)(by * 32 + ty + 8 * r) * N_DIM + bx * 32 + tx];
    __syncthreads();
#pragma unroll
    for (int r = 0; r < 4; r++)
        wt[(size_t)(bx * 32 + ty + 8 * r) * K_DIM + by * 32 + tx] = f2bf(tile[tx][ty + 8 * r]);
}

// ---------- 3) GEMM + bias + GELU ----------
// 128x128 tile, BK=64, 4 waves (2x2), wave does 64x64 via 4x4 MFMA 16x16x32 bf16.
// LDS chunk-XOR swizzle (chunk' = chunk ^ (row&7)) applied on the global source
// side of global_load_lds (dest must stay lane-contiguous); kills the 16-way
// bank conflict of the unswizzled row*128B layout.
// Operands swapped (W-frag first) so acc regs walk N -> float4 C stores.
__global__ __launch_bounds__(256) void gemm_kernel(const unsigned short* __restrict__ A,
                                                   const unsigned short* __restrict__ B,
                                                   const float* __restrict__ bias,
                                                   float* __restrict__ C) {
    __shared__ __attribute__((aligned(16))) unsigned short As[128 * 64];
    __shared__ __attribute__((aligned(16))) unsigned short Bs[128 * 64];

    int tid  = threadIdx.x;
    int lane = tid & 63;
    int wid  = tid >> 6;
    int waveM = wid >> 1;
    int waveN = wid & 1;
    int bm = blockIdx.y;
    int bn = blockIdx.x;

    f32x4 acc[4][4] = {};   // acc[i][j]: i -> N sub-tile (W), j -> M sub-tile (x)

    // staging: row = tid>>3 (+32*i), phys chunk = tid&7, source chunk swizzled
    int srow   = tid >> 3;
    int schunk = (tid & 7) ^ (srow & 7);
    const unsigned short* Ag = A + (size_t)(bm * 128 + srow) * K_DIM + schunk * 8;
    const unsigned short* Bg = B + (size_t)(bn * 128 + srow) * K_DIM + schunk * 8;
    unsigned short* Al = As + tid * 8;
    unsigned short* Bl = Bs + tid * 8;

    int mrow = lane & 15;
    int quad = lane >> 4;
    int swz  = mrow & 7;    // row&7 for all fragment rows (offsets are mult. of 16)

    for (int kt = 0; kt < K_DIM / 64; ++kt) {
#pragma unroll
        for (int i = 0; i < 4; i++) {
            async16(Ag + (size_t)i * 32 * K_DIM + kt * 64, Al + i * 2048);
            async16(Bg + (size_t)i * 32 * K_DIM + kt * 64, Bl + i * 2048);
        }
        __syncthreads();

#pragma unroll
        for (int s = 0; s < 2; s++) {
            int chunk = ((s * 4 + quad) ^ swz) * 8;   // swizzled k-chunk offset (shorts)
            bf16x8 wf[4], xf[4];
#pragma unroll
            for (int i = 0; i < 4; i++)
                wf[i] = *(const bf16x8*)(Bs + (waveN * 64 + i * 16 + mrow) * 64 + chunk);
#pragma unroll
            for (int j = 0; j < 4; j++)
                xf[j] = *(const bf16x8*)(As + (waveM * 64 + j * 16 + mrow) * 64 + chunk);
#pragma unroll
            for (int i = 0; i < 4; i++)
#pragma unroll
                for (int j = 0; j < 4; j++)
                    acc[i][j] = __builtin_amdgcn_mfma_f32_16x16x32_bf16(wf[i], xf[j], acc[i][j], 0, 0, 0);
        }
        __syncthreads();
    }

    // D layout: lane&15 -> B-operand row (m), quad*4+reg -> A-operand row (n)
    int m0 = bm * 128 + waveM * 64 + mrow;
    int n0 = bn * 128 + waveN * 64 + quad * 4;
#pragma unroll
    for (int i = 0; i < 4; i++) {
        f32x4 bb = *(const f32x4*)(bias + n0 + i * 16);
#pragma unroll
        for (int j = 0; j < 4; j++) {
            f32x4 o;
#pragma unroll
            for (int r = 0; r < 4; r++)
                o[r] = gelu_fast(acc[i][j][r] + bb[r]);
            *(f32x4*)(C + (size_t)(m0 + j * 16) * N_DIM + n0 + i * 16) = o;
        }
    }
}

extern "C" void kernel_launch(void* const* d_in, const int* in_sizes, int n_in,
                              void* d_out, int out_size, void* d_ws, size_t ws_size,
                              hipStream_t stream) {
    const float* x     = (const float*)d_in[0];
    const float* gamma = (const float*)d_in[1];
    const float* beta  = (const float*)d_in[2];
    const float* W     = (const float*)d_in[3];
    const float* bias  = (const float*)d_in[4];
    float* out = (float*)d_out;

    unsigned short* xn = (unsigned short*)d_ws;
    unsigned short* wt = xn + (size_t)M_ROWS * K_DIM;

    ln_kernel<<<M_ROWS / 4, 256, 0, stream>>>(x, gamma, beta, xn);
    wcast_kernel<<<dim3(N_DIM / 32, K_DIM / 32), dim3(32, 8), 0, stream>>>(W, wt);
    gemm_kernel<<<dim3(N_DIM / 128, M_ROWS / 128), 256, 0, stream>>>(xn, wt, bias, out);
}